// Round 1
// baseline (745.426 us; speedup 1.0000x reference)
//
#include <hip/hip_runtime.h>
#include <math.h>

// Problem constants (fixed by the reference's setup_inputs)
#define EPS_F 0.1f
#define L2E   1.44269504088896340736f   // log2(e)
#define SCALE (L2E / EPS_F)             // convert nats/EPS -> log2 units
constexpr int S = 16, H = 128, K = 64, B = 256, ITERS = 20;

// ---------- small device helpers ----------
template <int CTRL>
__device__ __forceinline__ float dpp_mov(float x, float old) {
  return __int_as_float(__builtin_amdgcn_update_dpp(
      __float_as_int(old), __float_as_int(x), CTRL, 0xF, 0xF, false));
}
// Full-wave (64-lane) reduction on the VALU pipe via DPP; result valid in lane 63.
__device__ __forceinline__ float wave_sum63(float x) {
  x += dpp_mov<0x111>(x, 0.f);   // row_shr:1
  x += dpp_mov<0x112>(x, 0.f);   // row_shr:2
  x += dpp_mov<0x114>(x, 0.f);   // row_shr:4
  x += dpp_mov<0x118>(x, 0.f);   // row_shr:8
  x += dpp_mov<0x142>(x, 0.f);   // row_bcast:15
  x += dpp_mov<0x143>(x, 0.f);   // row_bcast:31
  return x;
}
__device__ __forceinline__ float wave_max63(float x) {
  const float NI = -__builtin_inff();
  x = fmaxf(x, dpp_mov<0x111>(x, NI));
  x = fmaxf(x, dpp_mov<0x112>(x, NI));
  x = fmaxf(x, dpp_mov<0x114>(x, NI));
  x = fmaxf(x, dpp_mov<0x118>(x, NI));
  x = fmaxf(x, dpp_mov<0x142>(x, NI));
  x = fmaxf(x, dpp_mov<0x143>(x, NI));
  return x;
}
__device__ __forceinline__ float rl63(float x) {
  return __int_as_float(__builtin_amdgcn_readlane(__float_as_int(x), 63));
}
__device__ __forceinline__ float rfl(float x) {
  return __int_as_float(__builtin_amdgcn_readfirstlane(__float_as_int(x)));
}
#if __has_builtin(__builtin_amdgcn_exp2f)
__device__ __forceinline__ float ex2(float x) { return __builtin_amdgcn_exp2f(x); }
#else
__device__ __forceinline__ float ex2(float x) { return exp2f(x); }
#endif
#if __has_builtin(__builtin_amdgcn_logf)
__device__ __forceinline__ float lg2(float x) { return __builtin_amdgcn_logf(x); }
#else
__device__ __forceinline__ float lg2(float x) { return log2f(x); }
#endif

// ---------- prep: transpose+scale codebook, y^2, log-softmax prior ----------
__global__ void prep_kernel(const float* __restrict__ cb, const float* __restrict__ lp,
                            float* __restrict__ Z, float* __restrict__ y2s,
                            float* __restrict__ B2, float* __restrict__ prior) {
  const int t = threadIdx.x;  // one block of 256
  // Z stored as float4 chunks: Z4[c][k] = 2*SCALE*y[k][4c..4c+3], c in [0,32)
  for (int i = t; i < K * H / 4; i += 256) {
    const int c = i >> 6;
    const int k = i & 63;
    const float* p = cb + k * H + c * 4;
    float4 v;
    v.x = p[0] * (2.f * SCALE);
    v.y = p[1] * (2.f * SCALE);
    v.z = p[2] * (2.f * SCALE);
    v.w = p[3] * (2.f * SCALE);
    reinterpret_cast<float4*>(Z)[i] = v;
  }
  if (t < K) {
    const int k = t;
    float acc = 0.f;
    for (int d = 0; d < H; ++d) { const float v = cb[k * H + d]; acc = fmaf(v, v, acc); }
    y2s[k] = acc * SCALE;
    // log2-softmax of log_codebook_prior
    float m = -__builtin_inff();
    for (int j = 0; j < K; ++j) m = fmaxf(m, lp[j]);
    float s2 = 0.f;
    for (int j = 0; j < K; ++j) s2 += ex2((lp[j] - m) * L2E);
    const float b2 = (lp[k] - m) * L2E - lg2(s2);
    B2[k] = b2;           // log2(prior_k)
    prior[k] = ex2(b2);   // softmax fallback for empty graphs
  }
}

// ---------- main: one wave per node ----------
__global__ __launch_bounds__(256, 4)
void pool_kernel(const float* __restrict__ nd, const int* __restrict__ bidx,
                 const float* __restrict__ Z, const float* __restrict__ y2s,
                 const float* __restrict__ B2g,
                 float* __restrict__ sums, float* __restrict__ counts, int N) {
  __shared__ __align__(16) float xs[4][S * H];   // 32 KB: per-wave x tile
  __shared__ float x2l[4][S];                    // per-wave ||x_s||^2
  const int w = threadIdx.x >> 6;
  const int lane = threadIdx.x & 63;
  const int node = blockIdx.x * 4 + w;
  if (node >= N) return;

  // ---- stage x into LDS (coalesced float4), accumulate ||x_s||^2 on the fly ----
  const float* xp = nd + (size_t)node * (S * H);
  for (int c = 0; c < 8; ++c) {
    const int off = c * 256 + lane * 4;          // covers s = 2c + (lane>=32)
    const float4 v = *reinterpret_cast<const float4*>(xp + off);
    *reinterpret_cast<float4*>(&xs[w][off]) = v;
    float p = v.x * v.x + v.y * v.y + v.z * v.z + v.w * v.w;
    p += __shfl_xor(p, 1);
    p += __shfl_xor(p, 2);
    p += __shfl_xor(p, 4);
    p += __shfl_xor(p, 8);
    p += __shfl_xor(p, 16);                      // stays within each 32-lane half
    if ((lane & 31) == 0) x2l[w][c * 2 + (lane >> 5)] = p;
  }
  // Waves are independent; same-wave LDS RAW is ordered by compiler waitcnts.

  // ---- initial potentials: F0[s] = -(x2[s]-x2[0])*SCALE (trajectory-preserving shift) ----
  float F[S];   // wave-uniform; kept in SGPRs via readlane/readfirstlane
  {
    const float mu = x2l[w][0];
    #pragma unroll
    for (int s = 0; s < S; ++s) F[s] = rfl(-(x2l[w][s] - mu) * SCALE);
  }

  // ---- W[s] = (2*x_s.y_k - y_k^2) * SCALE for this lane's k ----
  float W[S];
  {
    const float y2k = y2s[lane];
    #pragma unroll
    for (int s = 0; s < S; ++s) W[s] = -y2k;
    const float4* Z4 = reinterpret_cast<const float4*>(Z);
    for (int c = 0; c < 32; ++c) {
      const float4 z = Z4[c * 64 + lane];        // coalesced, L1-hot
      #pragma unroll
      for (int s = 0; s < S; ++s) {
        const float4 x4 = *reinterpret_cast<const float4*>(&xs[w][s * H + c * 4]); // LDS broadcast
        W[s] = fmaf(x4.x, z.x, W[s]);
        W[s] = fmaf(x4.y, z.y, W[s]);
        W[s] = fmaf(x4.z, z.z, W[s]);
        W[s] = fmaf(x4.w, z.w, W[s]);
      }
    }
  }

  const float B2 = B2g[lane];
  float Gt = 0.f;

  // ---- 21 alternating (g,f) log-domain Sinkhorn updates (20 loop + final extrapolation) ----
  for (int it = 0; it <= ITERS; ++it) {
    // g-update: lse over s, in-lane (exact max)
    float tt[S];
    float m = -__builtin_inff();
    #pragma unroll
    for (int s = 0; s < S; ++s) { tt[s] = F[s] + W[s]; m = fmaxf(m, tt[s]); }
    float sum = 0.f;
    #pragma unroll
    for (int s = 0; s < S; ++s) sum += ex2(tt[s] - m);
    Gt = -(m + lg2(sum)) + B2;   // \tilde G = G + log2 b, per-lane (k)
    // f-update: lse over k = cross-lane DPP reduction (exact max)
    #pragma unroll
    for (int s = 0; s < S; ++s) {
      const float arg = Gt + W[s];
      const float mv = wave_max63(arg);
      const float ms = rl63(mv);
      const float e = ex2(arg - ms);
      const float sv = wave_sum63(e);
      F[s] = rl63(-(mv + lg2(sv)));
    }
  }

  // ---- transport-plan marginal histogram, normalize, atomically pool per graph ----
  float h = 0.f;
  #pragma unroll
  for (int s = 0; s < S; ++s) h += ex2(F[s] + Gt + W[s]);
  const float tot = rl63(wave_sum63(h));
  const float hn = h / (tot + 1e-12f);
  const int b = bidx[node];
  atomicAdd(&sums[b * K + lane], hn);
  if (lane == 0) atomicAdd(&counts[b], 1.f);
}

// ---------- finish: segment mean with prior fallback ----------
__global__ void finish_kernel(const float* __restrict__ sums, const float* __restrict__ counts,
                              const float* __restrict__ prior, float* __restrict__ out) {
  const int t = blockIdx.x * 256 + threadIdx.x;
  if (t >= B * K) return;
  const int b = t >> 6;
  const int k = t & 63;
  const float c = counts[b];
  out[t] = (c > 0.f) ? sums[t] / fmaxf(c, 1.f) : prior[k];
}

extern "C" void kernel_launch(void* const* d_in, const int* in_sizes, int n_in,
                              void* d_out, int out_size, void* d_ws, size_t ws_size,
                              hipStream_t stream) {
  const float* nd  = (const float*)d_in[0];   // [N,S,H] f32
  const int*   bx  = (const int*)d_in[1];     // [N] i32
  const float* cb  = (const float*)d_in[2];   // [K,H] f32
  const float* lp  = (const float*)d_in[3];   // [K] f32
  const int N = in_sizes[1];

  float* ws     = (float*)d_ws;
  float* sums   = ws;                  // B*K
  float* counts = ws + B * K;          // B
  float* Z      = counts + B;          // K*H (transposed+scaled codebook)
  float* y2s    = Z + K * H;           // K
  float* B2     = y2s + K;             // K
  float* prior  = B2 + K;              // K

  hipMemsetAsync(ws, 0, (size_t)(B * K + B) * sizeof(float), stream);
  prep_kernel<<<1, 256, 0, stream>>>(cb, lp, Z, y2s, B2, prior);
  pool_kernel<<<(N + 3) / 4, 256, 0, stream>>>(nd, bx, Z, y2s, B2, sums, counts, N);
  finish_kernel<<<(B * K + 255) / 256, 256, 0, stream>>>(sums, counts, prior, (float*)d_out);
}

// Round 2
// 566.236 us; speedup vs baseline: 1.3165x; 1.3165x over previous
//
#include <hip/hip_runtime.h>
#include <math.h>

// Problem constants (fixed by the reference's setup_inputs)
#define EPS_F 0.1f
#define L2E   1.44269504088896340736f   // log2(e)
#define SCALE (L2E / EPS_F)             // convert nats/EPS -> log2 units
constexpr int S = 16, H = 128, K = 64, B = 256, ITERS = 20;
constexpr int EXACT_IT = 3;             // exact-max iterations before shift-free phase

// ---------- small device helpers ----------
template <int CTRL>
__device__ __forceinline__ float dpp_mov(float x, float old) {
  return __int_as_float(__builtin_amdgcn_update_dpp(
      __float_as_int(old), __float_as_int(x), CTRL, 0xF, 0xF, false));
}
// Full-wave (64-lane) reduction on the VALU pipe via DPP; result valid in lane 63.
__device__ __forceinline__ float wave_sum63(float x) {
  x += dpp_mov<0x111>(x, 0.f);   // row_shr:1
  x += dpp_mov<0x112>(x, 0.f);   // row_shr:2
  x += dpp_mov<0x114>(x, 0.f);   // row_shr:4
  x += dpp_mov<0x118>(x, 0.f);   // row_shr:8
  x += dpp_mov<0x142>(x, 0.f);   // row_bcast:15
  x += dpp_mov<0x143>(x, 0.f);   // row_bcast:31
  return x;
}
__device__ __forceinline__ float wave_max63(float x) {
  const float NI = -__builtin_inff();
  x = fmaxf(x, dpp_mov<0x111>(x, NI));
  x = fmaxf(x, dpp_mov<0x112>(x, NI));
  x = fmaxf(x, dpp_mov<0x114>(x, NI));
  x = fmaxf(x, dpp_mov<0x118>(x, NI));
  x = fmaxf(x, dpp_mov<0x142>(x, NI));
  x = fmaxf(x, dpp_mov<0x143>(x, NI));
  return x;
}
__device__ __forceinline__ float rl63(float x) {
  return __int_as_float(__builtin_amdgcn_readlane(__float_as_int(x), 63));
}
__device__ __forceinline__ float rfl(float x) {
  return __int_as_float(__builtin_amdgcn_readfirstlane(__float_as_int(x)));
}
#if __has_builtin(__builtin_amdgcn_exp2f)
__device__ __forceinline__ float ex2(float x) { return __builtin_amdgcn_exp2f(x); }
#else
__device__ __forceinline__ float ex2(float x) { return exp2f(x); }
#endif
#if __has_builtin(__builtin_amdgcn_logf)
__device__ __forceinline__ float lg2(float x) { return __builtin_amdgcn_logf(x); }
#else
__device__ __forceinline__ float lg2(float x) { return log2f(x); }
#endif

// ---------- prep: transpose+scale codebook, y^2, log-softmax prior ----------
__global__ void prep_kernel(const float* __restrict__ cb, const float* __restrict__ lp,
                            float* __restrict__ Z, float* __restrict__ y2s,
                            float* __restrict__ B2, float* __restrict__ prior) {
  const int t = threadIdx.x;  // one block of 256
  // Z stored as float4 chunks: Z4[c][k] = 2*SCALE*y[k][4c..4c+3], c in [0,32)
  for (int i = t; i < K * H / 4; i += 256) {
    const int c = i >> 6;
    const int k = i & 63;
    const float* p = cb + k * H + c * 4;
    float4 v;
    v.x = p[0] * (2.f * SCALE);
    v.y = p[1] * (2.f * SCALE);
    v.z = p[2] * (2.f * SCALE);
    v.w = p[3] * (2.f * SCALE);
    reinterpret_cast<float4*>(Z)[i] = v;
  }
  if (t < K) {
    const int k = t;
    float acc = 0.f;
    for (int d = 0; d < H; ++d) { const float v = cb[k * H + d]; acc = fmaf(v, v, acc); }
    y2s[k] = acc * SCALE;
    // log2-softmax of log_codebook_prior
    float m = -__builtin_inff();
    for (int j = 0; j < K; ++j) m = fmaxf(m, lp[j]);
    float s2 = 0.f;
    for (int j = 0; j < K; ++j) s2 += ex2((lp[j] - m) * L2E);
    const float b2 = (lp[k] - m) * L2E - lg2(s2);
    B2[k] = b2;           // log2(prior_k)
    prior[k] = ex2(b2);   // softmax fallback for empty graphs
  }
}

// ---------- main: one wave per node ----------
__global__ __launch_bounds__(256, 4)
void pool_kernel(const float* __restrict__ nd, const int* __restrict__ bidx,
                 const float* __restrict__ Z, const float* __restrict__ y2s,
                 const float* __restrict__ B2g,
                 float* __restrict__ sums, float* __restrict__ counts, int N) {
  __shared__ __align__(16) float xs[4][S * H];   // 32 KB: per-wave x tile
  __shared__ float x2l[4][S];                    // per-wave ||x_s||^2
  const int w = threadIdx.x >> 6;
  const int lane = threadIdx.x & 63;
  const int node = blockIdx.x * 4 + w;
  if (node >= N) return;

  // ---- stage x into LDS (coalesced float4), accumulate ||x_s||^2 on the fly ----
  const float* xp = nd + (size_t)node * (S * H);
  for (int c = 0; c < 8; ++c) {
    const int off = c * 256 + lane * 4;          // covers s = 2c + (lane>=32)
    const float4 v = *reinterpret_cast<const float4*>(xp + off);
    *reinterpret_cast<float4*>(&xs[w][off]) = v;
    float p = v.x * v.x + v.y * v.y + v.z * v.z + v.w * v.w;
    p += __shfl_xor(p, 1);
    p += __shfl_xor(p, 2);
    p += __shfl_xor(p, 4);
    p += __shfl_xor(p, 8);
    p += __shfl_xor(p, 16);                      // stays within each 32-lane half
    if ((lane & 31) == 0) x2l[w][c * 2 + (lane >> 5)] = p;
  }
  // Waves are independent; same-wave LDS RAW is ordered by compiler waitcnts.

  // ---- initial potentials: F0[s] = -(x2[s]-x2[0])*SCALE (trajectory-preserving shift) ----
  float F[S];   // wave-uniform values (identical across lanes)
  {
    const float mu = x2l[w][0];
    #pragma unroll
    for (int s = 0; s < S; ++s) F[s] = rfl(-(x2l[w][s] - mu) * SCALE);
  }

  // ---- W[s] = (2*x_s.y_k - y_k^2) * SCALE for this lane's k ----
  float W[S];
  {
    const float y2k = y2s[lane];
    #pragma unroll
    for (int s = 0; s < S; ++s) W[s] = -y2k;
    const float4* Z4 = reinterpret_cast<const float4*>(Z);
    for (int c = 0; c < 32; ++c) {
      const float4 z = Z4[c * 64 + lane];        // coalesced, L1-hot
      #pragma unroll
      for (int s = 0; s < S; ++s) {
        const float4 x4 = *reinterpret_cast<const float4*>(&xs[w][s * H + c * 4]); // LDS broadcast
        W[s] = fmaf(x4.x, z.x, W[s]);
        W[s] = fmaf(x4.y, z.y, W[s]);
        W[s] = fmaf(x4.z, z.z, W[s]);
        W[s] = fmaf(x4.w, z.w, W[s]);
      }
    }
  }

  const float B2 = B2g[lane];
  float Gt = 0.f;

  // ---- phase 1: exact-max log-domain Sinkhorn (large early deltas) ----
  for (int it = 0; it < EXACT_IT; ++it) {
    // g-update: lse over s, in-lane (exact max)
    float tt[S];
    float m = -__builtin_inff();
    #pragma unroll
    for (int s = 0; s < S; ++s) { tt[s] = F[s] + W[s]; m = fmaxf(m, tt[s]); }
    float sum = 0.f;
    #pragma unroll
    for (int s = 0; s < S; ++s) sum += ex2(tt[s] - m);
    Gt = -(m + lg2(sum)) + B2;   // \tilde G = G + log2 b, per-lane (k)
    // f-update: lse over k = cross-lane DPP reduction (exact max)
    #pragma unroll
    for (int s = 0; s < S; ++s) {
      const float arg = Gt + W[s];
      const float mv = wave_max63(arg);
      const float ms = rl63(mv);
      const float e = ex2(arg - ms);
      const float sv = wave_sum63(e);
      F[s] = rl63(-(mv + lg2(sv)));
    }
  }

  // ---- phase 2: shift-free updates (prev potentials as lse shifts => sums ~ 1),
  //      clamp+floor guards make out-of-range early deltas self-correcting;
  //      early exit once the fixpoint is reached (remaining ref iters are identity) ----
  for (int it = EXACT_IT; it <= ITERS; ++it) {
    // g-update with shift = (B2 - Gt_prev):  Gt -= log2( sum_s 2^{F+W+Gt-B2} )
    const float sig = Gt - B2;
    float sg = 0.f;
    #pragma unroll
    for (int s = 0; s < S; ++s) sg += ex2(fminf(F[s] + W[s] + sig, 120.f));
    Gt -= lg2(fmaxf(sg, 1e-30f));
    // f-update with shift = -F_prev[s]:  F[s] -= log2( sum_k 2^{Gt+W+F_prev} )
    float dmax = 0.f;
    #pragma unroll
    for (int s = 0; s < S; ++s) {
      const float t = F[s] + Gt;                 // uniform + per-lane
      const float e = ex2(fminf(t + W[s], 120.f));
      const float sv = rl63(wave_sum63(e));
      const float d = lg2(fmaxf(sv, 1e-30f));    // uniform (from readlane)
      F[s] -= d;
      dmax = fmaxf(dmax, fabsf(d));
    }
    if (rfl(dmax) < 1e-6f) break;                // wave-uniform scalar branch
  }

  // ---- transport-plan marginal histogram, normalize, atomically pool per graph ----
  float h = 0.f;
  #pragma unroll
  for (int s = 0; s < S; ++s) h += ex2(F[s] + Gt + W[s]);
  const float tot = rl63(wave_sum63(h));
  const float hn = h / (tot + 1e-12f);
  const int b = bidx[node];
  atomicAdd(&sums[b * K + lane], hn);
  if (lane == 0) atomicAdd(&counts[b], 1.f);
}

// ---------- finish: segment mean with prior fallback ----------
__global__ void finish_kernel(const float* __restrict__ sums, const float* __restrict__ counts,
                              const float* __restrict__ prior, float* __restrict__ out) {
  const int t = blockIdx.x * 256 + threadIdx.x;
  if (t >= B * K) return;
  const int b = t >> 6;
  const int k = t & 63;
  const float c = counts[b];
  out[t] = (c > 0.f) ? sums[t] / fmaxf(c, 1.f) : prior[k];
}

extern "C" void kernel_launch(void* const* d_in, const int* in_sizes, int n_in,
                              void* d_out, int out_size, void* d_ws, size_t ws_size,
                              hipStream_t stream) {
  const float* nd  = (const float*)d_in[0];   // [N,S,H] f32
  const int*   bx  = (const int*)d_in[1];     // [N] i32
  const float* cb  = (const float*)d_in[2];   // [K,H] f32
  const float* lp  = (const float*)d_in[3];   // [K] f32
  const int N = in_sizes[1];

  float* ws     = (float*)d_ws;
  float* sums   = ws;                  // B*K
  float* counts = ws + B * K;          // B
  float* Z      = counts + B;          // K*H (transposed+scaled codebook)
  float* y2s    = Z + K * H;           // K
  float* B2     = y2s + K;             // K
  float* prior  = B2 + K;              // K

  hipMemsetAsync(ws, 0, (size_t)(B * K + B) * sizeof(float), stream);
  prep_kernel<<<1, 256, 0, stream>>>(cb, lp, Z, y2s, B2, prior);
  pool_kernel<<<(N + 3) / 4, 256, 0, stream>>>(nd, bx, Z, y2s, B2, sums, counts, N);
  finish_kernel<<<(B * K + 255) / 256, 256, 0, stream>>>(sums, counts, prior, (float*)d_out);
}